// Round 1
// baseline (89.819 us; speedup 1.0000x reference)
//
#include <hip/hip_runtime.h>

// Sinkhorn (loop-never-runs degenerate): out[b] = sum_{i,j} c * exp(-10*c),
// c = (xs_i - ys_j)^2 + (x_i - y_j)^2.  B=8, N=M=4096.
//
// Compute-bound (inputs 512 KB, cache-resident). VALU-issue was the limiter
// (6 VALU + 1 trans per element). This version:
//  - packed fp32 (v_pk_sub/mul/fma via float2 ext-vectors): halves VALU issues
//  - inputs prescaled by S = sqrt(10*log2 e), so exp argument is just -c'
//    (free neg input modifier on v_exp_f32) -> the per-element c*K mul is gone
//  - final sum rescaled once by ln(2)/10 = 1/S^2
// Per 2 elements: 5 packed VALU + 2 v_exp_f32 (was 12 VALU + 2 trans).

typedef float v2f __attribute__((ext_vector_type(2)));

constexpr int B_ = 8;
constexpr int N_ = 4096;
constexpr int M_ = 4096;
constexpr int THREADS = 256;
constexpr int ROWS_PER_BLOCK = 16;                       // 256 blocks/batch
constexpr int BLOCKS_PER_BATCH = N_ / ROWS_PER_BLOCK;    // 256
constexpr int TOTAL_BLOCKS = B_ * BLOCKS_PER_BATCH;      // 2048 -> 8 blocks/CU

__global__ __launch_bounds__(THREADS, 8) void sinkhorn_kernel(
    const float* __restrict__ x,  const float* __restrict__ y,
    const float* __restrict__ xs, const float* __restrict__ ys,
    float* __restrict__ out)
{
    const int b  = blockIdx.x >> 8;    // / BLOCKS_PER_BATCH
    const int rb = blockIdx.x & 255;   // % BLOCKS_PER_BATCH
    const int t  = threadIdx.x;

    constexpr float S    = 3.7982826f;     // sqrt(10*log2(e)); S^2 = 14.4269504
    constexpr float RCPS = 0.069314718f;   // ln(2)/10 = 1/S^2

    // Stage this block's 16 x-rows in LDS, PRESCALED by S. One ds_read_b64
    // broadcast per row in the main loop.
    __shared__ v2f s_x[ROWS_PER_BLOCK];    // {S*xs, S*x}
    const float* xrow  = x  + (size_t)b * N_ + rb * ROWS_PER_BLOCK;
    const float* xsrow = xs + (size_t)b * N_ + rb * ROWS_PER_BLOCK;
    if (t < ROWS_PER_BLOCK) {
        v2f v;
        v.x = xsrow[t] * S;
        v.y = xrow[t]  * S;
        s_x[t] = v;
    }

    // Each thread holds 16 y columns (4 x float4 coalesced), prescaled by S,
    // repacked as float2 pairs for packed-fp32 math.
    const float4* yv4 = reinterpret_cast<const float4*>(y  + (size_t)b * M_);
    const float4* ys4 = reinterpret_cast<const float4*>(ys + (size_t)b * M_);
    v2f yv[8], yg[8];
#pragma unroll
    for (int k = 0; k < 4; ++k) {
        const float4 a = yv4[k * THREADS + t];
        const float4 g = ys4[k * THREADS + t];
        yv[2*k+0] = v2f{a.x, a.y} * S;
        yv[2*k+1] = v2f{a.z, a.w} * S;
        yg[2*k+0] = v2f{g.x, g.y} * S;
        yg[2*k+1] = v2f{g.z, g.w} * S;
    }
    __syncthreads();

    v2f acc0 = {0.0f, 0.0f}, acc1 = {0.0f, 0.0f};

#pragma unroll 4
    for (int r = 0; r < ROWS_PER_BLOCK; ++r) {
        const v2f xr = s_x[r];             // LDS broadcast (ds_read_b64)
        const v2f sx = {xr.x, xr.x};
        const v2f vx = {xr.y, xr.y};
#pragma unroll
        for (int k = 0; k < 8; k += 2) {
            // pair A -> acc0
            v2f d0a = sx - yg[k+0];                                  // v_pk_add (neg)
            v2f d1a = vx - yv[k+0];
            v2f ca  = __builtin_elementwise_fma(d1a, d1a, d0a * d0a); // pk_mul+pk_fma
            v2f ea;
            ea.x = __builtin_amdgcn_exp2f(-ca.x);                    // v_exp_f32, -src mod
            ea.y = __builtin_amdgcn_exp2f(-ca.y);
            acc0 = __builtin_elementwise_fma(ca, ea, acc0);          // v_pk_fma

            // pair B -> acc1 (independent chain)
            v2f d0b = sx - yg[k+1];
            v2f d1b = vx - yv[k+1];
            v2f cb  = __builtin_elementwise_fma(d1b, d1b, d0b * d0b);
            v2f eb;
            eb.x = __builtin_amdgcn_exp2f(-cb.x);
            eb.y = __builtin_amdgcn_exp2f(-cb.y);
            acc1 = __builtin_elementwise_fma(cb, eb, acc1);
        }
    }

    const v2f accv = acc0 + acc1;
    float acc = accv.x + accv.y;

    // wave (64-lane) shuffle reduce
#pragma unroll
    for (int off = 32; off > 0; off >>= 1)
        acc += __shfl_down(acc, off, 64);

    __shared__ float wsum[THREADS / 64];
    const int lane = t & 63, wid = t >> 6;
    if (lane == 0) wsum[wid] = acc;
    __syncthreads();
    if (t == 0) {
        float s = 0.0f;
#pragma unroll
        for (int w = 0; w < THREADS / 64; ++w) s += wsum[w];
        atomicAdd(&out[b], s * RCPS);   // undo the S^2 prescale once
    }
}

extern "C" void kernel_launch(void* const* d_in, const int* in_sizes, int n_in,
                              void* d_out, int out_size, void* d_ws, size_t ws_size,
                              hipStream_t stream) {
    const float* x  = (const float*)d_in[0];
    const float* y  = (const float*)d_in[1];
    const float* xs = (const float*)d_in[2];
    const float* ys = (const float*)d_in[3];
    float* out = (float*)d_out;

    // d_out is poisoned 0xAA before every launch — zero it (capture-safe).
    hipMemsetAsync(out, 0, (size_t)out_size * sizeof(float), stream);

    sinkhorn_kernel<<<TOTAL_BLOCKS, THREADS, 0, stream>>>(x, y, xs, ys, out);
}